// Round 6
// baseline (33682.318 us; speedup 1.0000x reference)
//
#include <hip/hip_runtime.h>

typedef __attribute__((ext_vector_type(8))) short bhalf8;
typedef __attribute__((ext_vector_type(4))) float floatx4;

#define NSLOTS 502
#define NWG 240
#define BLOCK 768

#define AS1 __attribute__((address_space(1)))
#define AS3 __attribute__((address_space(3)))
// global->LDS direct, 16B/lane. aux=17 = sc0|sc1 (coherent, MALL-served).
#define GLL_COH(g, s) __builtin_amdgcn_global_load_lds((const AS1 unsigned*)(g), (AS3 unsigned*)(s), 16, 0, 17)

__device__ __forceinline__ unsigned short f2b(float f) {
  unsigned u = __float_as_uint(f);
  return (unsigned short)((u + 0x7FFFu + ((u >> 16) & 1u)) >> 16);
}
__device__ __forceinline__ unsigned long long cload(const unsigned long long* p) {
  return __hip_atomic_load(p, __ATOMIC_RELAXED, __HIP_MEMORY_SCOPE_AGENT);
}
__device__ __forceinline__ int cloadi(const int* p) {
  return __hip_atomic_load(p, __ATOMIC_RELAXED, __HIP_MEMORY_SCOPE_AGENT);
}
__device__ __forceinline__ void cstorei(int* p, int v) {
  __hip_atomic_store(p, v, __ATOMIC_RELAXED, __HIP_MEMORY_SCOPE_AGENT);
}
__device__ __forceinline__ void cstoreu(unsigned* p, unsigned v) {
  __hip_atomic_store(p, v, __ATOMIC_RELAXED, __HIP_MEMORY_SCOPE_AGENT);
}
__device__ __forceinline__ void cstoref(float* p, float v) {
  __hip_atomic_store(p, v, __ATOMIC_RELAXED, __HIP_MEMORY_SCOPE_AGENT);
}

__global__ void prep_w(const float* __restrict__ wih, const float* __restrict__ whh,
                       const float* __restrict__ wout,
                       unsigned short* __restrict__ wihb, unsigned short* __restrict__ whhb,
                       unsigned short* __restrict__ woutb) {
  size_t i0 = (size_t)blockIdx.x * blockDim.x + threadIdx.x;
  size_t stride = (size_t)gridDim.x * blockDim.x;
  for (size_t i = i0; i < 6291456u; i += stride) { wihb[i] = f2b(wih[i]); whhb[i] = f2b(whh[i]); }
  for (size_t i = i0; i < 163840u; i += stride) woutb[i] = f2b(wout[i]);
}

// ws layout (bytes):
// 0        flags (240 int, monotonic completed-slot counters), pad 1024
// 1024     h0b[3] x 131072  (bf16 64x1024)
// 394240   h1b[2] x 131072
// --- zero region ends 656384 ---
// 656384   gi0 ring: 8 slots x 64x3072 f32 = 6291456  -> 6947840
// 6947840  Woutb 327680                               -> 7275520
// 7275520  Wihb  12582912                             -> 19858432
// 19858432 Whhb  12582912                             -> 32441344

__launch_bounds__(BLOCK, 3)
__global__ void gru_main(const float* __restrict__ res,
                         const unsigned short* __restrict__ wihb,
                         const unsigned short* __restrict__ whhb,
                         const unsigned short* __restrict__ woutb,
                         const float* __restrict__ bih, const float* __restrict__ bhh,
                         const float* __restrict__ bout,
                         char* __restrict__ wsb, float* __restrict__ out) {
  int* flg = (int*)wsb;
  char* h0p0 = wsb + 1024;  char* h0p1 = wsb + 132096; char* h0p2 = wsb + 263168;
  char* h1p0 = wsb + 394240; char* h1p1 = wsb + 525312;
  float* gi0 = (float*)(wsb + 656384);

  const int wg = blockIdx.x;
  const int tid = threadIdx.x;
  const int w = tid >> 6;
  const int l = tid & 63;
  const int l15 = l & 15, l4 = l >> 4;

  __shared__ __align__(16) char smem[131072];

  if (wg < 48) {
    // ================= PRODUCER: gi0(s) = x(s) @ Wih0^T (cols p*64..+64) ========
    const int p = wg;
    int dead = 0;
    for (int s = 0; s < NSLOTS; ++s) {
      if (s <= 499) {
        // stage x(s) (B=64 x H=1024 bf16) from res (B,H,T) f32 -- plain scattered loads
        if (w >= 4) {
          #pragma unroll
          for (int i = 0; i < 16; ++i) {
            int gidx = (w - 4) * 16 + i;
            int r = gidx >> 1, hh = gidx & 1;
            const float* sp = res + ((size_t)r * 1024 + hh * 512 + l * 8) * 500 + s;
            union { bhalf8 v; unsigned short us[8]; } pk;
            #pragma unroll
            for (int e = 0; e < 8; ++e) pk.us[e] = f2b(sp[e * 500]);
            *(bhalf8*)(smem + r * 2048 + ((hh * 1024 + l * 16) ^ ((r & 7) << 4))) = pk.v;
          }
        }
        __syncthreads();
        floatx4 acc[4];
        #pragma unroll
        for (int m = 0; m < 4; ++m) acc[m] = (floatx4){0.f, 0.f, 0.f, 0.f};
        if (w < 4) {
          const unsigned short* brow = wihb + (size_t)(p * 64 + w * 16 + l15) * 1024 + l4 * 8;
          #pragma unroll
          for (int ks = 0; ks < 32; ++ks) {
            bhalf8 bb = *(const bhalf8*)(brow + ks * 32);
            #pragma unroll
            for (int m = 0; m < 4; ++m) {
              int row = m * 16 + l15;
              bhalf8 a = *(const bhalf8*)(smem + row * 2048 + ((ks * 64 + l4 * 16) ^ ((row & 7) << 4)));
              acc[m] = __builtin_amdgcn_mfma_f32_16x16x32_bf16(a, bb, acc[m], 0, 0, 0);
            }
          }
        }
        // ring-overwrite throttle: need all L0 WGs past slot s-7
        if (w == 0 && !dead) {
          int it = 0;
          while (!__all(cloadi(&flg[48 + l]) >= s - 6)) {
            __builtin_amdgcn_s_sleep(1);
            if (++it > 3000000) { dead = 1; break; }
          }
        }
        __syncthreads();
        if (w < 4) {
          float* ring = gi0 + (size_t)(s & 7) * 196608;
          int cg = p * 64 + w * 16 + l15;
          #pragma unroll
          for (int m = 0; m < 4; ++m)
            #pragma unroll
            for (int i = 0; i < 4; ++i)
              cstoref(ring + (size_t)(m * 16 + l4 * 4 + i) * 3072 + cg, acc[m][i]);
        }
        __syncthreads();   // drain gi0 stores before flag
      }
      if (tid == 0) cstorei(&flg[wg], s + 1);
    }
  } else if (wg < 112) {
    // ================= L0: h0(s) = GRU(gi0(s), h0(s-1)); cols c*16..+16 =========
    const int c = wg - 48, n0c = c * 16;
    const int g = w >> 2, kh = w & 3;   // 12 waves = 3 gates x 4 k-quarters
    const unsigned short* wbase = whhb + (size_t)(g * 1024 + n0c + l15) * 1024 + kh * 256 + l4 * 8;
    bhalf8 wreg[8];
    #pragma unroll
    for (int i = 0; i < 8; ++i) wreg[i] = *(const bhalf8*)(wbase + i * 32);
    const int j0t = (tid & 7) << 1;
    float bir[3][2], bhr[3][2];
    #pragma unroll
    for (int gg = 0; gg < 3; ++gg)
      #pragma unroll
      for (int q = 0; q < 2; ++q) {
        bir[gg][q] = bih[gg * 1024 + n0c + j0t + q];
        bhr[gg][q] = bhh[gg * 1024 + n0c + j0t + q];
      }
    float hcr[2] = {0.f, 0.f};
    int dead = 0;
    for (int s = 0; s < NSLOTS; ++s) {
      #pragma unroll
      for (int i = 0; i < 8; ++i) asm volatile("" : "+v"(wreg[i]));
      if (s <= 499) {
        if (w == 0 && !dead) {
          int it = 0;
          for (;;) {
            int fa = (l < 48) ? cloadi(&flg[l]) : 0x7fffffff;   // producers: gi0(s) ready
            int fb = cloadi(&flg[48 + l]);                      // L0 peers: h0(s-1)
            int fc = cloadi(&flg[112 + l]);                     // L1: buffer hazard
            int fd = cloadi(&flg[176 + l]);
            int ok = (fa >= s + 1) && (fb >= s) && (fc >= s - 1) && (fd >= s - 1);
            if (__all(ok)) break;
            __builtin_amdgcn_s_sleep(1);
            if (++it > 3000000) { dead = 1; break; }
          }
        }
        __builtin_amdgcn_s_barrier();
        __builtin_amdgcn_sched_barrier(0);
        int bsel = (s + 2) % 3;
        const char* h0src = (bsel == 0) ? h0p0 : (bsel == 1) ? h0p1 : h0p2;
        if (w < 8) {   // one-burst gather of h0(s-1): 128 x 1KB, single exposed RTT
          #pragma unroll
          for (int i = 0; i < 16; ++i) {
            int idx = w + i * 8;
            int row = idx >> 1, hh = idx & 1;
            GLL_COH(h0src + row * 2048 + ((hh * 1024 + l * 16) ^ ((row & 7) << 4)),
                    smem + idx * 1024);
          }
        }
        unsigned long long gv[3] = {0, 0, 0};
        if (tid < 512) {   // gi0 slice into registers (coherent), hidden under MFMA phase
          const char* ringp = (const char*)gi0 + (size_t)(s & 7) * 786432;
          int b = tid >> 3;
          #pragma unroll
          for (int gg = 0; gg < 3; ++gg)
            gv[gg] = cload((const unsigned long long*)(ringp + (((size_t)b * 3072 + gg * 1024 + n0c + j0t) << 2)));
        }
        asm volatile("s_waitcnt vmcnt(0)" ::: "memory");
        __builtin_amdgcn_s_barrier();
        __builtin_amdgcn_sched_barrier(0);
        floatx4 acc[4];
        #pragma unroll
        for (int m = 0; m < 4; ++m) acc[m] = (floatx4){0.f, 0.f, 0.f, 0.f};
        #pragma unroll
        for (int ks = 0; ks < 8; ++ks)
          #pragma unroll
          for (int m = 0; m < 4; ++m) {
            int row = m * 16 + l15;
            bhalf8 a = *(const bhalf8*)(smem + row * 2048 +
                       ((kh * 512 + ks * 64 + l4 * 16) ^ ((row & 7) << 4)));
            acc[m] = __builtin_amdgcn_mfma_f32_16x16x32_bf16(a, wreg[ks], acc[m], 0, 0, 0);
          }
        __syncthreads();
        float* Gsf = (float*)smem;   // 12 planes [64][18] f32 overlay
        #pragma unroll
        for (int m = 0; m < 4; ++m)
          #pragma unroll
          for (int i = 0; i < 4; ++i)
            Gsf[w * 1152 + (m * 16 + l4 * 4 + i) * 18 + l15] = acc[m][i];
        __syncthreads();
        if (tid < 512) {
          int b = tid >> 3;
          char* hout = (s % 3 == 0) ? h0p0 : (s % 3 == 1) ? h0p1 : h0p2;
          union { unsigned u32; unsigned short us[2]; } pk;
          #pragma unroll
          for (int q = 0; q < 2; ++q) {
            int j = j0t + q;
            float gi_r = __uint_as_float((unsigned)(gv[0] >> (q * 32)));
            float gi_z = __uint_as_float((unsigned)(gv[1] >> (q * 32)));
            float gi_n = __uint_as_float((unsigned)(gv[2] >> (q * 32)));
            float hs[3];
            #pragma unroll
            for (int gg = 0; gg < 3; ++gg) {
              float t = 0.f;
              #pragma unroll
              for (int k2 = 0; k2 < 4; ++k2) t += Gsf[(gg * 4 + k2) * 1152 + b * 18 + j];
              hs[gg] = t;
            }
            float ir = gi_r + bir[0][q], iz = gi_z + bir[1][q], inn = gi_n + bir[2][q];
            float hr = hs[0] + bhr[0][q], hz = hs[1] + bhr[1][q], hn = hs[2] + bhr[2][q];
            float rg = 1.f / (1.f + expf(-(ir + hr)));
            float zg = 1.f / (1.f + expf(-(iz + hz)));
            float nc = tanhf(inn + rg * hn);
            float hp = hcr[q];
            float hnew = (1.f - zg) * nc + zg * hp;
            float hzo = 0.1f * hp + 0.9f * hnew;   // eval-mode zoneout
            hcr[q] = hzo;
            pk.us[q] = f2b(hzo);
          }
          cstoreu((unsigned*)(hout + (size_t)b * 2048 + ((n0c + j0t) << 1)), pk.u32);
        }
      }
      __syncthreads();
      if (tid == 0) cstorei(&flg[wg], s + 1);
    }
  } else {
    // ====== L1: h1(s-1) = GRU(h0(s-1), h1(s-2)); cols cc*16..+16, rows bh*32..+32
    const int idx1 = wg - 112;
    const int bh_ = idx1 >> 6, cc = idx1 & 63;
    const int n0c = cc * 16, rb = bh_ * 32;
    const int sd = w / 6, gq = (w % 6) >> 1, kh = w & 1;  // side x gate x k-half
    const unsigned short* Wsd = (sd ? whhb : wihb) + 3145728;  // layer 1
    const unsigned short* wbase = Wsd + (size_t)(gq * 1024 + n0c + l15) * 1024 + kh * 512 + l4 * 8;
    bhalf8 wreg[16];
    #pragma unroll
    for (int i = 0; i < 16; ++i) wreg[i] = *(const bhalf8*)(wbase + i * 32);
    const int j0t = (tid & 7) << 1;
    float bir[3][2], bhr[3][2];
    #pragma unroll
    for (int gg = 0; gg < 3; ++gg)
      #pragma unroll
      for (int q = 0; q < 2; ++q) {
        bir[gg][q] = bih[3072 + gg * 1024 + n0c + j0t + q];
        bhr[gg][q] = bhh[3072 + gg * 1024 + n0c + j0t + q];
      }
    float hcr[2] = {0.f, 0.f};
    int dead = 0;
    for (int s = 0; s < NSLOTS; ++s) {
      #pragma unroll
      for (int i = 0; i < 16; ++i) asm volatile("" : "+v"(wreg[i]));
      if (s >= 1) {
        if (w == 0 && !dead) {
          int it = 0;
          for (;;) {
            int fb = cloadi(&flg[48 + l]);
            int fc = cloadi(&flg[112 + l]);
            int fd = cloadi(&flg[176 + l]);
            int ok = (fb >= s) && (fc >= s) && (fd >= s);
            if (__all(ok)) break;
            __builtin_amdgcn_s_sleep(1);
            if (++it > 3000000) { dead = 1; break; }
          }
        }
        __builtin_amdgcn_s_barrier();
        __builtin_amdgcn_sched_barrier(0);
        int bsel = (s + 2) % 3;
        const char* h0src = ((bsel == 0) ? h0p0 : (bsel == 1) ? h0p1 : h0p2) + (size_t)rb * 2048;
        const char* h1src = ((s & 1) ? h1p1 : h1p0) + (size_t)rb * 2048;
        if (w < 8) {   // one-burst gather: h0 half-plane + h1 half-plane (128 x 1KB)
          #pragma unroll
          for (int i = 0; i < 16; ++i) {
            int id2 = w + i * 8;
            int pl = id2 >> 6, r6 = id2 & 63;
            int row = r6 >> 1, hh = r6 & 1;
            GLL_COH((pl ? h1src : h0src) + row * 2048 + ((hh * 1024 + l * 16) ^ ((row & 7) << 4)),
                    smem + pl * 65536 + r6 * 1024);
          }
        }
        asm volatile("s_waitcnt vmcnt(0)" ::: "memory");
        __builtin_amdgcn_s_barrier();
        __builtin_amdgcn_sched_barrier(0);
        if (s <= 500) {
          floatx4 acc[2];
          acc[0] = (floatx4){0.f, 0.f, 0.f, 0.f};
          acc[1] = (floatx4){0.f, 0.f, 0.f, 0.f};
          #pragma unroll
          for (int ks = 0; ks < 16; ++ks)
            #pragma unroll
            for (int m = 0; m < 2; ++m) {
              int row = m * 16 + l15;
              bhalf8 a = *(const bhalf8*)(smem + sd * 65536 + row * 2048 +
                         ((kh * 1024 + ks * 64 + l4 * 16) ^ ((row & 7) << 4)));
              acc[m] = __builtin_amdgcn_mfma_f32_16x16x32_bf16(a, wreg[ks], acc[m], 0, 0, 0);
            }
          __syncthreads();
          float* Gsf = (float*)smem;   // 12 planes [32][18] f32 (overlay h0 half only)
          #pragma unroll
          for (int m = 0; m < 2; ++m)
            #pragma unroll
            for (int i = 0; i < 4; ++i)
              Gsf[w * 576 + (m * 16 + l4 * 4 + i) * 18 + l15] = acc[m][i];
          __syncthreads();
          if (tid < 256) {
            int lr = tid >> 3;
            char* hout = ((s & 1) ? h1p0 : h1p1);
            union { unsigned u32; unsigned short us[2]; } pk;
            #pragma unroll
            for (int q = 0; q < 2; ++q) {
              int j = j0t + q;
              float is_[3], hs[3];
              #pragma unroll
              for (int gg = 0; gg < 3; ++gg) {
                is_[gg] = Gsf[(gg * 2 + 0) * 576 + lr * 18 + j] + Gsf[(gg * 2 + 1) * 576 + lr * 18 + j];
                hs[gg]  = Gsf[(6 + gg * 2 + 0) * 576 + lr * 18 + j] + Gsf[(6 + gg * 2 + 1) * 576 + lr * 18 + j];
              }
              float ir = is_[0] + bir[0][q], iz = is_[1] + bir[1][q], inn = is_[2] + bir[2][q];
              float hr = hs[0] + bhr[0][q], hz = hs[1] + bhr[1][q], hn = hs[2] + bhr[2][q];
              float rg = 1.f / (1.f + expf(-(ir + hr)));
              float zg = 1.f / (1.f + expf(-(iz + hz)));
              float nc = tanhf(inn + rg * hn);
              float hp = hcr[q];
              float hnew = (1.f - zg) * nc + zg * hp;
              float hzo = 0.1f * hp + 0.9f * hnew;
              hcr[q] = hzo;
              pk.us[q] = f2b(hzo);
            }
            cstoreu((unsigned*)(hout + (size_t)(rb + lr) * 2048 + ((n0c + j0t) << 1)), pk.u32);
          }
        }
      }
      __syncthreads();
      if (tid == 0) cstorei(&flg[wg], s + 1);
      // y(s-2) = h1(s-2) @ Wout^T + bout from the RESIDENT h1 LDS plane (slack work)
      if (s >= 2 && cc < 10 && w < 2) {
        const unsigned short* brow = woutb + (size_t)(cc * 16 + l15) * 1024 + l4 * 8;
        floatx4 accy = (floatx4){0.f, 0.f, 0.f, 0.f};
        #pragma unroll
        for (int ks = 0; ks < 32; ++ks) {
          int row = w * 16 + l15;
          bhalf8 a = *(const bhalf8*)(smem + 65536 + row * 2048 +
                     ((ks * 64 + l4 * 16) ^ ((row & 7) << 4)));
          bhalf8 bb = *(const bhalf8*)(brow + ks * 32);
          accy = __builtin_amdgcn_mfma_f32_16x16x32_bf16(a, bb, accy, 0, 0, 0);
        }
        int col = cc * 16 + l15, t2 = s - 2;
        float bo = bout[col];
        #pragma unroll
        for (int i = 0; i < 4; ++i) {
          int b = rb + w * 16 + l4 * 4 + i;
          out[(size_t)b * 80000 + (size_t)(col >> 1) * 1000 + t2 * 2 + (col & 1)] = accy[i] + bo;
        }
      }
    }
  }
}

extern "C" void kernel_launch(void* const* d_in, const int* in_sizes, int n_in,
                              void* d_out, int out_size, void* d_ws, size_t ws_size,
                              hipStream_t stream) {
  const float* res  = (const float*)d_in[0];
  const float* Wih  = (const float*)d_in[1];
  const float* Whh  = (const float*)d_in[2];
  const float* bih  = (const float*)d_in[3];
  const float* bhh  = (const float*)d_in[4];
  const float* Wout = (const float*)d_in[5];
  const float* bout = (const float*)d_in[6];
  float* out = (float*)d_out;
  char* ws = (char*)d_ws;
  if (ws_size < 32441344u) return;  // workspace too small; fail loudly via wrong output

  unsigned short* woutb = (unsigned short*)(ws + 6947840);
  unsigned short* wihb  = (unsigned short*)(ws + 7275520);
  unsigned short* whhb  = (unsigned short*)(ws + 19858432);

  // zero flags + h state (h0 x3, h1 x2)
  hipMemsetAsync(ws, 0, 656384, stream);
  prep_w<<<4096, 256, 0, stream>>>(Wih, Whh, Wout, wihb, whhb, woutb);
  gru_main<<<NWG, BLOCK, 0, stream>>>(res, wihb, whhb, woutb, bih, bhh, bout, ws, out);
}

// Round 8
// 15894.122 us; speedup vs baseline: 2.1192x; 2.1192x over previous
//
#include <hip/hip_runtime.h>

typedef __attribute__((ext_vector_type(8))) short bhalf8;
typedef __attribute__((ext_vector_type(4))) float floatx4;

#define NSLOTS 502
#define NWG 128
#define BLOCK 768   // 12 waves = side(2) x gate(3) x col-half(2)

#define AS1 __attribute__((address_space(1)))
#define AS3 __attribute__((address_space(3)))
// global->LDS direct, 16B/lane. aux=17 = sc0|sc1 (coherent, cross-XCD fresh). aux=0 cached.
#define GLL_COH(g, s)   __builtin_amdgcn_global_load_lds((const AS1 unsigned*)(g), (AS3 unsigned*)(s), 16, 0, 17)
#define GLL_PLAIN(g, s) __builtin_amdgcn_global_load_lds((const AS1 unsigned*)(g), (AS3 unsigned*)(s), 16, 0, 0)

__device__ __forceinline__ unsigned short f2b(float f) {
  unsigned u = __float_as_uint(f);
  return (unsigned short)((u + 0x7FFFu + ((u >> 16) & 1u)) >> 16);
}
__device__ __forceinline__ int cloadi(const int* p) {
  return __hip_atomic_load(p, __ATOMIC_RELAXED, __HIP_MEMORY_SCOPE_AGENT);
}
__device__ __forceinline__ void cstorei(int* p, int v) {
  __hip_atomic_store(p, v, __ATOMIC_RELAXED, __HIP_MEMORY_SCOPE_AGENT);
}
__device__ __forceinline__ void cstore(unsigned long long* p, unsigned long long v) {
  __hip_atomic_store(p, v, __ATOMIC_RELAXED, __HIP_MEMORY_SCOPE_AGENT);
}

__global__ void prep_w(const float* __restrict__ wih, const float* __restrict__ whh,
                       const float* __restrict__ wout,
                       unsigned short* __restrict__ wihb, unsigned short* __restrict__ whhb,
                       unsigned short* __restrict__ woutb) {
  size_t i0 = (size_t)blockIdx.x * blockDim.x + threadIdx.x;
  size_t stride = (size_t)gridDim.x * blockDim.x;
  for (size_t i = i0; i < 6291456u; i += stride) { wihb[i] = f2b(wih[i]); whhb[i] = f2b(whh[i]); }
  for (size_t i = i0; i < 163840u; i += stride) woutb[i] = f2b(wout[i]);
}

// res_output (B=64, H=1024, T=500) f32 -> xb (T, B, H) bf16  (coalesced transpose)
__global__ void prep_x(const float* __restrict__ x, unsigned short* __restrict__ xb) {
  __shared__ float tile[32][33];
  int b = blockIdx.z;
  int h0 = blockIdx.y * 32, t0 = blockIdx.x * 32;
  int tx = threadIdx.x, ty = threadIdx.y;
  #pragma unroll
  for (int i = 0; i < 32; i += 8) {
    int t = t0 + tx;
    if (t < 500) tile[ty + i][tx] = x[((size_t)b * 1024 + h0 + ty + i) * 500 + t];
  }
  __syncthreads();
  #pragma unroll
  for (int i = 0; i < 32; i += 8) {
    int t = t0 + ty + i;
    if (t < 500) xb[((size_t)t * 64 + b) * 1024 + h0 + tx] = f2b(tile[tx][ty + i]);
  }
}

// ws layout (bytes):
// 0        flags (128 int monotonic, store-only), pad 1024
// 1024     h0b[3] x 131072  (bf16 64x1024)
// 394240   h1b[2] x 131072
// --- zero region ends 656384 ---
// 656384   Woutb  327680    -> 984064
// 984064   Wihb   12582912  -> 13566976
// 13566976 Whhb   12582912  -> 26149888
// 26149888 Xb (500*64*1024 bf16) -> 91685888

__launch_bounds__(BLOCK, 3)
__global__ void gru_main(const unsigned short* __restrict__ xb,
                         const unsigned short* __restrict__ wihb,
                         const unsigned short* __restrict__ whhb,
                         const unsigned short* __restrict__ woutb,
                         const float* __restrict__ bih, const float* __restrict__ bhh,
                         const float* __restrict__ bout,
                         char* __restrict__ wsb, float* __restrict__ out) {
  int* flg = (int*)wsb;
  char* h0p[3] = { wsb + 1024, wsb + 132096, wsb + 263168 };
  char* h1p[2] = { wsb + 394240, wsb + 525312 };

  const int wg = blockIdx.x;
  const int layer = wg >> 6;          // 0: 64 WGs compute h0(s); 1: 64 WGs compute h1(s-1)
  const int sub = wg & 63;
  const int eta = sub >> 5;           // batch half: rows [eta*32, +32)
  const int c = sub & 31;             // col slice: n in [c*32, +32)
  const int n0c = c * 32;
  const int rb = eta * 32;
  const int tid = threadIdx.x;
  const int w = tid >> 6;             // wave 0..11
  const int l = tid & 63;
  const int l15 = l & 15, l4 = l >> 4;
  const int sd = w / 6;               // side 0=input, 1=recurrent
  const int g = (w % 6) >> 1;         // gate r,z,n
  const int u = w & 1;                // col half (16 cols)

  // LDS: [0,64K) side-0 operand (32 rows x 2048B, src-swizzled), [64K,128K) side-1.
  // Gs gate planes (12 x [32][18] f32 = 27KB) overlay [0,..) after the GEMMs.
  __shared__ __align__(16) char smem[131072];

  // weights streamed from L2 inside the MFMA loop (R4-proven: cheap, no VGPR games)
  const unsigned short* Wsd = (sd ? whhb : wihb) + (size_t)layer * 3145728;
  const unsigned short* wrow = Wsd + (size_t)(g * 1024 + n0c + u * 16 + l15) * 1024 + l4 * 8;

  // bias regs for the static epilogue mapping (tid<256 -> lr=tid>>3, j0=(tid&7)*4)
  float bir[3][4], bhr[3][4];
  {
    int j0 = (tid & 7) << 2;
    #pragma unroll
    for (int q = 0; q < 4; ++q)
      #pragma unroll
      for (int gg = 0; gg < 3; ++gg) {
        bir[gg][q] = bih[layer * 3072 + gg * 1024 + n0c + j0 + q];
        bhr[gg][q] = bhh[layer * 3072 + gg * 1024 + n0c + j0 + q];
      }
  }
  float hcr[4] = {0.f, 0.f, 0.f, 0.f};   // fp32 zoneout carry (static per-thread)
  int dead = 0;

  for (int s = 0; s < NSLOTS; ++s) {
    if (layer == 0) {
      // ================= L0: h0(s) = GRU(x(s), h0(s-1)) =================
      if (s <= 499) {
        // pre-poll x-stage (plain cached; data is static)
        const char* xsrc = (const char*)xb + (size_t)s * 131072 + (size_t)rb * 2048;
        #pragma unroll
        for (int i = 0; i < 6; ++i) {
          int idx = w + i * 12;
          if (idx < 64) {
            int row = idx >> 1, hh = idx & 1;
            GLL_PLAIN(xsrc + row * 2048 + ((hh * 1024 + l * 16) ^ ((row & 7) << 4)),
                      smem + idx * 1024);
          }
        }
        // store-only flag poll (lane-parallel, no RMW)
        if (w == 0 && !dead) {
          int it = 0;
          for (;;) {
            int f0 = cloadi(&flg[l]);
            int f1 = cloadi(&flg[64 + l]);
            if (__all(f0 >= s && f1 >= s - 1)) break;   // peers h0(s-1); L1 buffer hazard
            __builtin_amdgcn_s_sleep(1);
            if (++it > 500000) { dead = 1; break; }     // bounded failsafe
          }
        }
        asm volatile("s_waitcnt vmcnt(0)" ::: "memory");   // x loads drained
        __builtin_amdgcn_s_barrier();
        __builtin_amdgcn_sched_barrier(0);
        // single-burst coherent gather of h0(s-1) half-plane: ONE exposed RTT
        const char* h0src = h0p[(s + 2) % 3] + (size_t)rb * 2048;
        #pragma unroll
        for (int i = 0; i < 6; ++i) {
          int idx = w + i * 12;
          if (idx < 64) {
            int row = idx >> 1, hh = idx & 1;
            GLL_COH(h0src + row * 2048 + ((hh * 1024 + l * 16) ^ ((row & 7) << 4)),
                    smem + 65536 + idx * 1024);
          }
        }
        asm volatile("s_waitcnt vmcnt(0)" ::: "memory");
        __builtin_amdgcn_s_barrier();
        __builtin_amdgcn_sched_barrier(0);
        // GEMM: wave (sd,g,u): 2 m-tiles x 16 cols x K=1024
        const char* Ab = smem + sd * 65536;
        floatx4 acc[2];
        acc[0] = (floatx4){0.f, 0.f, 0.f, 0.f};
        acc[1] = (floatx4){0.f, 0.f, 0.f, 0.f};
        #pragma unroll
        for (int ks = 0; ks < 32; ++ks) {
          bhalf8 bb = *(const bhalf8*)(wrow + ks * 32);   // streamed from L2
          #pragma unroll
          for (int m = 0; m < 2; ++m) {
            int row = m * 16 + l15;
            bhalf8 a = *(const bhalf8*)(Ab + row * 2048 + ((ks * 64 + l4 * 16) ^ ((row & 7) << 4)));
            acc[m] = __builtin_amdgcn_mfma_f32_16x16x32_bf16(a, bb, acc[m], 0, 0, 0);
          }
        }
        __syncthreads();
        float* Gsf = (float*)smem;   // overlay on side-0 buf
        #pragma unroll
        for (int m = 0; m < 2; ++m)
          #pragma unroll
          for (int i = 0; i < 4; ++i)
            Gsf[w * 576 + (m * 16 + l4 * 4 + i) * 18 + l15] = acc[m][i];
        __syncthreads();
        if (tid < 256) {
          int lr = tid >> 3, j0 = (tid & 7) << 2;
          char* hout = h0p[s % 3];
          union { unsigned long long ull; unsigned short us[4]; } pk;
          #pragma unroll
          for (int q = 0; q < 4; ++q) {
            int j = j0 + q, u_ = j >> 4, jj = j & 15;
            float ir  = Gsf[(0 + u_) * 576 + lr * 18 + jj] + bir[0][q];
            float iz  = Gsf[(2 + u_) * 576 + lr * 18 + jj] + bir[1][q];
            float inn = Gsf[(4 + u_) * 576 + lr * 18 + jj] + bir[2][q];
            float hr  = Gsf[(6 + u_) * 576 + lr * 18 + jj] + bhr[0][q];
            float hz  = Gsf[(8 + u_) * 576 + lr * 18 + jj] + bhr[1][q];
            float hn  = Gsf[(10 + u_) * 576 + lr * 18 + jj] + bhr[2][q];
            float rg = 1.f / (1.f + expf(-(ir + hr)));
            float zg = 1.f / (1.f + expf(-(iz + hz)));
            float nc = tanhf(inn + rg * hn);
            float hp = hcr[q];
            float hnew = (1.f - zg) * nc + zg * hp;
            float hzo = 0.1f * hp + 0.9f * hnew;   // eval-mode zoneout
            hcr[q] = hzo;
            pk.us[q] = f2b(hzo);
          }
          cstore((unsigned long long*)(hout + (size_t)(rb + lr) * 2048 + ((n0c + j0) << 1)), pk.ull);
        }
      }
      __syncthreads();   // drains coherent h-stores before the flag
      if (tid == 0) cstorei(&flg[wg], s + 1);
    } else {
      // ===== L1: h1(s-1) = GRU(h0(s-1), h1(s-2)); y(s-2) from resident h1 =====
      const bool gemm = (s >= 1 && s <= 500);
      if (s >= 1) {
        if (w == 0 && !dead) {
          int it = 0;
          for (;;) {
            int f0 = cloadi(&flg[l]);
            int f1 = cloadi(&flg[64 + l]);
            if (__all(f0 >= s && f1 >= s)) break;   // h0(s-1) ready; peers h1(s-2) ready
            __builtin_amdgcn_s_sleep(1);
            if (++it > 500000) { dead = 1; break; }
          }
        }
        __builtin_amdgcn_s_barrier();
        __builtin_amdgcn_sched_barrier(0);
        const char* h0src = h0p[(s + 2) % 3] + (size_t)rb * 2048;
        const char* h1src = h1p[s & 1] + (size_t)rb * 2048;
        if (gemm) {   // both half-planes in ONE burst (128 x 1KB): one exposed RTT
          #pragma unroll
          for (int i = 0; i < 11; ++i) {
            int idx = w + i * 12;
            if (idx < 128) {
              int pl = idx >> 6, r6 = idx & 63;
              int row = r6 >> 1, hh = r6 & 1;
              GLL_COH((pl ? h1src : h0src) + row * 2048 + ((hh * 1024 + l * 16) ^ ((row & 7) << 4)),
                      smem + pl * 65536 + r6 * 1024);
            }
          }
        } else {      // s == 501: h1(499) only, for the final y
          #pragma unroll
          for (int i = 0; i < 6; ++i) {
            int idx = w + i * 12;
            if (idx < 64) {
              int row = idx >> 1, hh = idx & 1;
              GLL_COH(h1src + row * 2048 + ((hh * 1024 + l * 16) ^ ((row & 7) << 4)),
                      smem + 65536 + idx * 1024);
            }
          }
        }
        asm volatile("s_waitcnt vmcnt(0)" ::: "memory");
        __builtin_amdgcn_s_barrier();
        __builtin_amdgcn_sched_barrier(0);
        floatx4 acc[2];
        acc[0] = (floatx4){0.f, 0.f, 0.f, 0.f};
        acc[1] = (floatx4){0.f, 0.f, 0.f, 0.f};
        if (gemm) {
          const char* Ab = smem + sd * 65536;
          #pragma unroll
          for (int ks = 0; ks < 32; ++ks) {
            bhalf8 bb = *(const bhalf8*)(wrow + ks * 32);
            #pragma unroll
            for (int m = 0; m < 2; ++m) {
              int row = m * 16 + l15;
              bhalf8 a = *(const bhalf8*)(Ab + row * 2048 + ((ks * 64 + l4 * 16) ^ ((row & 7) << 4)));
              acc[m] = __builtin_amdgcn_mfma_f32_16x16x32_bf16(a, bb, acc[m], 0, 0, 0);
            }
          }
        }
        // y(s-2) = h1(s-2) @ Wout^T + bout from the RESIDENT h1 half-plane
        if (s >= 2 && c < 5 && w < 2) {
          int t2 = s - 2;
          #pragma unroll
          for (int nt = 0; nt < 2; ++nt) {
            int col = c * 32 + nt * 16 + l15;
            const unsigned short* brow = woutb + (size_t)col * 1024 + l4 * 8;
            floatx4 accy = (floatx4){0.f, 0.f, 0.f, 0.f};
            #pragma unroll
            for (int ks = 0; ks < 32; ++ks) {
              int row = w * 16 + l15;
              bhalf8 a = *(const bhalf8*)(smem + 65536 + row * 2048 +
                         ((ks * 64 + l4 * 16) ^ ((row & 7) << 4)));
              bhalf8 bb = *(const bhalf8*)(brow + ks * 32);
              accy = __builtin_amdgcn_mfma_f32_16x16x32_bf16(a, bb, accy, 0, 0, 0);
            }
            float bo = bout[col];
            #pragma unroll
            for (int i = 0; i < 4; ++i) {
              int b = rb + w * 16 + l4 * 4 + i;
              out[(size_t)b * 80000 + (size_t)(col >> 1) * 1000 + t2 * 2 + (col & 1)] = accy[i] + bo;
            }
          }
        }
        if (gemm) {
          __syncthreads();
          float* Gsf = (float*)smem;   // overlay on h0 buf only; h1 buf stays for y
          #pragma unroll
          for (int m = 0; m < 2; ++m)
            #pragma unroll
            for (int i = 0; i < 4; ++i)
              Gsf[w * 576 + (m * 16 + l4 * 4 + i) * 18 + l15] = acc[m][i];
          __syncthreads();
          if (tid < 256) {
            int lr = tid >> 3, j0 = (tid & 7) << 2;
            char* hout = h1p[(s & 1) ^ 1];
            union { unsigned long long ull; unsigned short us[4]; } pk;
            #pragma unroll
            for (int q = 0; q < 4; ++q) {
              int j = j0 + q, u_ = j >> 4, jj = j & 15;
              float ir  = Gsf[(0 + u_) * 576 + lr * 18 + jj] + bir[0][q];
              float iz  = Gsf[(2 + u_) * 576 + lr * 18 + jj] + bir[1][q];
              float inn = Gsf[(4 + u_) * 576 + lr * 18 + jj] + bir[2][q];
              float hr  = Gsf[(6 + u_) * 576 + lr * 18 + jj] + bhr[0][q];
              float hz  = Gsf[(8 + u_) * 576 + lr * 18 + jj] + bhr[1][q];
              float hn  = Gsf[(10 + u_) * 576 + lr * 18 + jj] + bhr[2][q];
              float rg = 1.f / (1.f + expf(-(ir + hr)));
              float zg = 1.f / (1.f + expf(-(iz + hz)));
              float nc = tanhf(inn + rg * hn);
              float hp = hcr[q];
              float hnew = (1.f - zg) * nc + zg * hp;
              float hzo = 0.1f * hp + 0.9f * hnew;
              hcr[q] = hzo;
              pk.us[q] = f2b(hzo);
            }
            cstore((unsigned long long*)(hout + (size_t)(rb + lr) * 2048 + ((n0c + j0) << 1)), pk.ull);
          }
        }
      }
      __syncthreads();
      if (tid == 0) cstorei(&flg[wg], s + 1);
    }
  }
}

extern "C" void kernel_launch(void* const* d_in, const int* in_sizes, int n_in,
                              void* d_out, int out_size, void* d_ws, size_t ws_size,
                              hipStream_t stream) {
  const float* res  = (const float*)d_in[0];
  const float* Wih  = (const float*)d_in[1];
  const float* Whh  = (const float*)d_in[2];
  const float* bih  = (const float*)d_in[3];
  const float* bhh  = (const float*)d_in[4];
  const float* Wout = (const float*)d_in[5];
  const float* bout = (const float*)d_in[6];
  float* out = (float*)d_out;
  char* ws = (char*)d_ws;
  if (ws_size < 91685888u) return;  // workspace too small; fail loudly via wrong output

  unsigned short* woutb = (unsigned short*)(ws + 656384);
  unsigned short* wihb  = (unsigned short*)(ws + 984064);
  unsigned short* whhb  = (unsigned short*)(ws + 13566976);
  unsigned short* xb    = (unsigned short*)(ws + 26149888);

  // zero flags + h state (h0 x3, h1 x2)
  hipMemsetAsync(ws, 0, 656384, stream);
  prep_w<<<4096, 256, 0, stream>>>(Wih, Whh, Wout, wihb, whhb, woutb);
  prep_x<<<dim3(16, 32, 64), dim3(32, 8), 0, stream>>>(res, xb);
  gru_main<<<NWG, BLOCK, 0, stream>>>(xb, wihb, whhb, woutb, bih, bhh, bout, ws, out);
}